// Round 1
// baseline (303.089 us; speedup 1.0000x reference)
//
#include <hip/hip_runtime.h>

// LieRE: out[n,y,x,q,:] = in[n,y,x,q,:] @ expm(y_v*S0 + x_v*S1)
// N=32,H=32,W=32,h=16,d=64. Transpose symmetry: rot[31-y][31-x] = rot[y][x]^T.

typedef float f4 __attribute__((ext_vector_type(4)));
typedef short s8v __attribute__((ext_vector_type(8)));
typedef float f32x4 __attribute__((ext_vector_type(4)));

constexpr int LST = 68;   // fp32 LDS row stride (floats): breaks pow2 bank strides, keeps 16B align
constexpr int BST = 72;   // bf16 LDS row stride (ushorts): 144B rows -> 2-way max on frag reads

static __device__ __forceinline__ unsigned short f2bf(float f) {
    // round-to-nearest-even fp32 -> bf16 (inputs are finite, no NaN handling needed)
    unsigned int u = __float_as_uint(f);
    u += 0x7fffu + ((u >> 16) & 1u);
    return (unsigned short)(u >> 16);
}

// C = A*B + cI*I   (64x64, fp32 in LDS, 256 threads, each owns a 4x4 block)
static __device__ __forceinline__ void mm(float* __restrict__ C,
                                          const float* __restrict__ A,
                                          const float* __restrict__ B,
                                          float cI, int tid) {
    const int r0 = (tid >> 4) << 2;
    const int c0 = (tid & 15) << 2;
    f4 acc0 = {0.f, 0.f, 0.f, 0.f}, acc1 = acc0, acc2 = acc0, acc3 = acc0;
#pragma unroll 4
    for (int k = 0; k < 64; k += 4) {
        f4 b0 = *(const f4*)&B[(k + 0) * LST + c0];
        f4 b1 = *(const f4*)&B[(k + 1) * LST + c0];
        f4 b2 = *(const f4*)&B[(k + 2) * LST + c0];
        f4 b3 = *(const f4*)&B[(k + 3) * LST + c0];
        f4 a0 = *(const f4*)&A[(r0 + 0) * LST + k];
        f4 a1 = *(const f4*)&A[(r0 + 1) * LST + k];
        f4 a2 = *(const f4*)&A[(r0 + 2) * LST + k];
        f4 a3 = *(const f4*)&A[(r0 + 3) * LST + k];
        acc0 += a0.x * b0; acc0 += a0.y * b1; acc0 += a0.z * b2; acc0 += a0.w * b3;
        acc1 += a1.x * b0; acc1 += a1.y * b1; acc1 += a1.z * b2; acc1 += a1.w * b3;
        acc2 += a2.x * b0; acc2 += a2.y * b1; acc2 += a2.z * b2; acc2 += a2.w * b3;
        acc3 += a3.x * b0; acc3 += a3.y * b1; acc3 += a3.z * b2; acc3 += a3.w * b3;
    }
    if (r0 == c0) { acc0.x += cI; acc1.y += cI; acc2.z += cI; acc3.w += cI; }
    *(f4*)&C[(r0 + 0) * LST + c0] = acc0;
    *(f4*)&C[(r0 + 1) * LST + c0] = acc1;
    *(f4*)&C[(r0 + 2) * LST + c0] = acc2;
    *(f4*)&C[(r0 + 3) * LST + c0] = acc3;
}

__global__ __launch_bounds__(256, 2)
void liere_fused(const float* __restrict__ in, const float* __restrict__ emb,
                 float* __restrict__ out) {
    __shared__ __align__(16) float sA[64 * LST];  // gen (scaled); later RT(bf16)+Astage(bf16)
    __shared__ __align__(16) float sU[64 * LST];
    __shared__ __align__(16) float sV[64 * LST];
    __shared__ float snorm;

    const int tid = threadIdx.x;
    const int p = blockIdx.x;          // 0..511
    const int y = p >> 5;              // 0..15
    const int x = p & 31;              // 0..31

    // ---- stage emb[0] -> sU, emb[1] -> sV (padded rows) ----
#pragma unroll
    for (int i = 0; i < 4; ++i) {
        int lin = i * 1024 + tid * 4;
        int r = lin >> 6, c = lin & 63;
        *(f4*)&sU[r * LST + c] = *(const f4*)&emb[lin];
        *(f4*)&sV[r * LST + c] = *(const f4*)&emb[4096 + lin];
    }
    __syncthreads();

    // ---- build gen into sA ----
    const float yv = (2.0f * (float)y - 31.0f) / 31.0f;
    const float xv = (2.0f * (float)x - 31.0f) / 31.0f;
    {
        const int r0 = (tid >> 4) << 2, c0 = (tid & 15) << 2;
#pragma unroll
        for (int i = 0; i < 4; ++i)
#pragma unroll
            for (int j = 0; j < 4; ++j) {
                int r = r0 + i, c = c0 + j;
                float s0, s1;
                if (r < c)      { s0 = sU[r * LST + c];  s1 = sV[r * LST + c]; }
                else if (r > c) { s0 = -sU[c * LST + r]; s1 = -sV[c * LST + r]; }
                else            { s0 = 0.f; s1 = 0.f; }
                sA[r * LST + c] = yv * s0 + xv * s1;
            }
    }
    __syncthreads();

    // ---- 1-norm (= max abs row sum for skew) by wave 0 ----
    if (tid < 64) {
        float s = 0.f;
        for (int c = 0; c < 64; ++c) s += fabsf(sA[tid * LST + c]);
#pragma unroll
        for (int off = 32; off > 0; off >>= 1) s = fmaxf(s, __shfl_down(s, off, 64));
        if (tid == 0) snorm = s;
    }
    __syncthreads();
    int sq = 0;
    {
        float nm = snorm;
        if (nm > 1.0f) sq = (int)ceilf(log2f(nm));
        if (sq < 0) sq = 0;
        if (sq > 14) sq = 14;
    }
    const float scale = exp2f((float)(-sq));

    // Taylor coeffs 1/k!
    const float C9 = 2.75573192e-6f, C8 = 2.48015876e-5f, C7 = 1.98412701e-4f,
                C6 = 1.38888893e-3f, C5 = 8.33333377e-3f, C4 = 4.16666679e-2f,
                C3 = 0.166666672f,   C2 = 0.5f,           C1 = 1.0f, C0 = 1.0f;

    // ---- scale A, init T = C9*A + C8*I into sU (overwrites emb copy) ----
    {
        const int r0 = (tid >> 4) << 2, c0 = (tid & 15) << 2;
#pragma unroll
        for (int i = 0; i < 4; ++i)
#pragma unroll
            for (int j = 0; j < 4; ++j) {
                int r = r0 + i, c = c0 + j;
                float a = sA[r * LST + c] * scale;
                sA[r * LST + c] = a;
                sU[r * LST + c] = C9 * a + ((r == c) ? C8 : 0.f);
            }
    }
    __syncthreads();

    // ---- Horner: 8 matmuls, degree-9 Taylor of exp(A) ----
    mm(sV, sU, sA, C7, tid); __syncthreads();
    mm(sU, sV, sA, C6, tid); __syncthreads();
    mm(sV, sU, sA, C5, tid); __syncthreads();
    mm(sU, sV, sA, C4, tid); __syncthreads();
    mm(sV, sU, sA, C3, tid); __syncthreads();
    mm(sU, sV, sA, C2, tid); __syncthreads();
    mm(sV, sU, sA, C1, tid); __syncthreads();
    mm(sU, sV, sA, C0, tid); __syncthreads();

    // ---- squarings ----
    float* cur = sU;
    float* oth = sV;
    for (int i = 0; i < sq; ++i) {
        mm(oth, cur, cur, 0.f, tid);
        __syncthreads();
        float* t = cur; cur = oth; oth = t;
    }
    // cur = R = expm(gen) for position (y,x), fp32, stride LST

    // ---- apply phase: bf16 MFMA, two positions (pair via transpose) ----
    unsigned short* RT = (unsigned short*)sA;                 // [64][BST] bf16, RT[c][k] = R[k][c]
    unsigned short* AS = (unsigned short*)(sA + 2304);        // byte off 9216 (16B aligned), [16][BST]

    const int w = tid >> 6;        // wave 0..3 -> col tile
    const int lane = tid & 63;
    const int m = lane & 15;
    const int q4 = lane >> 4;

    for (int pass = 0; pass < 2; ++pass) {
        __syncthreads();
        // build RT: pass 0: RT[c][k] = cur[k][c] (R itself); pass 1: RT[c][k] = cur[c][k] (R^T)
        {
            int c = tid >> 2;
            int k0 = (tid & 3) << 4;
            for (int k = k0; k < k0 + 16; ++k) {
                float v = pass ? cur[c * LST + k] : cur[k * LST + c];
                RT[c * BST + k] = f2bf(v);
            }
        }
        __syncthreads();

        const int yy = pass ? (31 - y) : y;
        const int xx = pass ? (31 - x) : x;

        for (int n = 0; n < 32; ++n) {
            const size_t off = ((size_t)((n * 32 + yy) * 32 + xx)) * 1024;
            const float* src = in + off;
            float* dst = out + off;

            // stage 16x64 fp32 -> bf16 tile (rows = h index, cols = d)
            {
                f4 v = *(const f4*)(src + tid * 4);
                int q = tid >> 4, col = (tid & 15) << 2;
                unsigned int lo = (unsigned int)f2bf(v.x) | ((unsigned int)f2bf(v.y) << 16);
                unsigned int hi = (unsigned int)f2bf(v.z) | ((unsigned int)f2bf(v.w) << 16);
                unsigned int* d2 = (unsigned int*)&AS[q * BST + col];
                d2[0] = lo;
                d2[1] = hi;
            }
            __syncthreads();

            {
                // A-frag: rows m of input tile, k = q4*8 + j (+32 for second MFMA)
                const s8v a0 = *(const s8v*)&AS[m * BST + q4 * 8];
                const s8v a1 = *(const s8v*)&AS[m * BST + 32 + q4 * 8];
                // B-frag: B[k][n] = R[k][w*16+n] = RT[w*16+n][k], n = m
                const s8v b0 = *(const s8v*)&RT[(w * 16 + m) * BST + q4 * 8];
                const s8v b1 = *(const s8v*)&RT[(w * 16 + m) * BST + 32 + q4 * 8];
                f32x4 acc = {0.f, 0.f, 0.f, 0.f};
                acc = __builtin_amdgcn_mfma_f32_16x16x32_bf16(a0, b0, acc, 0, 0, 0);
                acc = __builtin_amdgcn_mfma_f32_16x16x32_bf16(a1, b1, acc, 0, 0, 0);
                // D: col = lane&15 (= n), row = q4*4 + reg
#pragma unroll
                for (int r = 0; r < 4; ++r)
                    dst[(q4 * 4 + r) * 64 + w * 16 + m] = acc[r];
            }
            __syncthreads();
        }
    }
}

extern "C" void kernel_launch(void* const* d_in, const int* in_sizes, int n_in,
                              void* d_out, int out_size, void* d_ws, size_t ws_size,
                              hipStream_t stream) {
    (void)in_sizes; (void)n_in; (void)out_size; (void)d_ws; (void)ws_size;
    const float* in = (const float*)d_in[0];
    const float* emb = (const float*)d_in[1];
    float* out = (float*)d_out;
    hipLaunchKernelGGL(liere_fused, dim3(512), dim3(256), 0, stream, in, emb, out);
}

// Round 3
// 280.038 us; speedup vs baseline: 1.0823x; 1.0823x over previous
//
#include <hip/hip_runtime.h>

// LieRE: out[n,y,x,q,:] = in[n,y,x,q,:] @ expm(y_v*S0 + x_v*S1)
// N=32,H=32,W=32,h=16,d=64. Transpose symmetry: rot[31-y][31-x] = rot[y][x]^T.
// Phase 1 (per block): expm via scale-and-square + degree-9 Taylor Horner, fp32 in LDS.
// Phase 2: barrier-free apply. R-fragments hoisted to registers; input streams
// global->reg (bf16 cvt)->MFMA->global. No LDS in the hot loop.
// NOTE: batch (n) stride is H*W*h*d = 1<<20 floats. (Round-2 bug: used 32768.)

typedef float f4 __attribute__((ext_vector_type(4)));
typedef short s8v __attribute__((ext_vector_type(8)));
typedef float f32x4 __attribute__((ext_vector_type(4)));

constexpr int LST = 68;   // fp32 LDS row stride (floats)
constexpr int BST = 72;   // bf16 LDS row stride (ushorts); 144B rows, 16B-aligned

static __device__ __forceinline__ unsigned short f2bf(float f) {
    unsigned int u = __float_as_uint(f);
    u += 0x7fffu + ((u >> 16) & 1u);
    return (unsigned short)(u >> 16);
}

// C = A*B + cI*I   (64x64 fp32 in LDS, 256 threads, 4x4 block per thread)
static __device__ __forceinline__ void mm(float* __restrict__ C,
                                          const float* __restrict__ A,
                                          const float* __restrict__ B,
                                          float cI, int tid) {
    const int r0 = (tid >> 4) << 2;
    const int c0 = (tid & 15) << 2;
    f4 acc0 = {0.f, 0.f, 0.f, 0.f}, acc1 = acc0, acc2 = acc0, acc3 = acc0;
#pragma unroll 4
    for (int k = 0; k < 64; k += 4) {
        f4 b0 = *(const f4*)&B[(k + 0) * LST + c0];
        f4 b1 = *(const f4*)&B[(k + 1) * LST + c0];
        f4 b2 = *(const f4*)&B[(k + 2) * LST + c0];
        f4 b3 = *(const f4*)&B[(k + 3) * LST + c0];
        f4 a0 = *(const f4*)&A[(r0 + 0) * LST + k];
        f4 a1 = *(const f4*)&A[(r0 + 1) * LST + k];
        f4 a2 = *(const f4*)&A[(r0 + 2) * LST + k];
        f4 a3 = *(const f4*)&A[(r0 + 3) * LST + k];
        acc0 += a0.x * b0; acc0 += a0.y * b1; acc0 += a0.z * b2; acc0 += a0.w * b3;
        acc1 += a1.x * b0; acc1 += a1.y * b1; acc1 += a1.z * b2; acc1 += a1.w * b3;
        acc2 += a2.x * b0; acc2 += a2.y * b1; acc2 += a2.z * b2; acc2 += a2.w * b3;
        acc3 += a3.x * b0; acc3 += a3.y * b1; acc3 += a3.z * b2; acc3 += a3.w * b3;
    }
    if (r0 == c0) { acc0.x += cI; acc1.y += cI; acc2.z += cI; acc3.w += cI; }
    *(f4*)&C[(r0 + 0) * LST + c0] = acc0;
    *(f4*)&C[(r0 + 1) * LST + c0] = acc1;
    *(f4*)&C[(r0 + 2) * LST + c0] = acc2;
    *(f4*)&C[(r0 + 3) * LST + c0] = acc3;
}

__global__ __launch_bounds__(256, 2)
void liere_fused(const float* __restrict__ in, const float* __restrict__ emb,
                 float* __restrict__ out) {
    __shared__ __align__(16) float sA[64 * LST];
    __shared__ __align__(16) float sU[64 * LST];
    __shared__ __align__(16) float sV[64 * LST];
    __shared__ float snorm;

    const int tid = threadIdx.x;
    const int p = blockIdx.x;          // 0..511
    const int y = p >> 5;              // 0..15
    const int x = p & 31;              // 0..31

    // ---- stage emb[0] -> sU, emb[1] -> sV ----
#pragma unroll
    for (int i = 0; i < 4; ++i) {
        int lin = i * 1024 + tid * 4;
        int r = lin >> 6, c = lin & 63;
        *(f4*)&sU[r * LST + c] = *(const f4*)&emb[lin];
        *(f4*)&sV[r * LST + c] = *(const f4*)&emb[4096 + lin];
    }
    __syncthreads();

    // ---- build gen into sA ----
    const float yv = (2.0f * (float)y - 31.0f) / 31.0f;
    const float xv = (2.0f * (float)x - 31.0f) / 31.0f;
    {
        const int r0 = (tid >> 4) << 2, c0 = (tid & 15) << 2;
#pragma unroll
        for (int i = 0; i < 4; ++i)
#pragma unroll
            for (int j = 0; j < 4; ++j) {
                int r = r0 + i, c = c0 + j;
                float s0, s1;
                if (r < c)      { s0 = sU[r * LST + c];  s1 = sV[r * LST + c]; }
                else if (r > c) { s0 = -sU[c * LST + r]; s1 = -sV[c * LST + r]; }
                else            { s0 = 0.f; s1 = 0.f; }
                sA[r * LST + c] = yv * s0 + xv * s1;
            }
    }
    __syncthreads();

    // ---- 1-norm by wave 0 ----
    if (tid < 64) {
        float s = 0.f;
        for (int c = 0; c < 64; ++c) s += fabsf(sA[tid * LST + c]);
#pragma unroll
        for (int off = 32; off > 0; off >>= 1) s = fmaxf(s, __shfl_down(s, off, 64));
        if (tid == 0) snorm = s;
    }
    __syncthreads();
    int sq = 0;
    {
        float nm = snorm;
        if (nm > 1.0f) sq = (int)ceilf(log2f(nm));
        if (sq < 0) sq = 0;
        if (sq > 14) sq = 14;
    }
    const float scale = exp2f((float)(-sq));

    const float C9 = 2.75573192e-6f, C8 = 2.48015876e-5f, C7 = 1.98412701e-4f,
                C6 = 1.38888893e-3f, C5 = 8.33333377e-3f, C4 = 4.16666679e-2f,
                C3 = 0.166666672f,   C2 = 0.5f,           C1 = 1.0f, C0 = 1.0f;

    // ---- scale A, init T = C9*A + C8*I into sU ----
    {
        const int r0 = (tid >> 4) << 2, c0 = (tid & 15) << 2;
#pragma unroll
        for (int i = 0; i < 4; ++i)
#pragma unroll
            for (int j = 0; j < 4; ++j) {
                int r = r0 + i, c = c0 + j;
                float a = sA[r * LST + c] * scale;
                sA[r * LST + c] = a;
                sU[r * LST + c] = C9 * a + ((r == c) ? C8 : 0.f);
            }
    }
    __syncthreads();

    // ---- Horner: 8 matmuls ----
    mm(sV, sU, sA, C7, tid); __syncthreads();
    mm(sU, sV, sA, C6, tid); __syncthreads();
    mm(sV, sU, sA, C5, tid); __syncthreads();
    mm(sU, sV, sA, C4, tid); __syncthreads();
    mm(sV, sU, sA, C3, tid); __syncthreads();
    mm(sU, sV, sA, C2, tid); __syncthreads();
    mm(sV, sU, sA, C1, tid); __syncthreads();
    mm(sU, sV, sA, C0, tid); __syncthreads();

    // ---- squarings ----
    float* cur = sU;
    float* oth = sV;
    for (int i = 0; i < sq; ++i) {
        mm(oth, cur, cur, 0.f, tid);
        __syncthreads();
        float* t = cur; cur = oth; oth = t;
    }
    // cur = R (fp32, stride LST)

    // ---- build bf16 copies: Rb[r][k]=R[r][k] (pass1), RT[c][k]=R[k][c] (pass0) ----
    unsigned short* Rb = (unsigned short*)sA;    // 64 x BST bf16
    unsigned short* RT = (unsigned short*)oth;   // 64 x BST bf16 (not cur)
    {
        const int r = tid >> 2;
        const int k0 = (tid & 3) << 4;
        for (int k = k0; k < k0 + 16; ++k) {
            unsigned short b = f2bf(cur[r * LST + k]);
            Rb[r * BST + k] = b;
            RT[k * BST + r] = b;
        }
    }
    __syncthreads();

    // ---- apply: barrier-free, per-wave independent ----
    // out^T = A_op * B_op: A_op[m][k] = R[k][t*16+m] (pass0, from RT) or
    // R[t*16+m][k] (pass1, from Rb); B_op[k][n] = in[h=n][k].
    // A-frag: A[m=lane&15][k=q4*8+j]; B-frag: B[k=q4*8+j][n=lane&15];
    // D: col=lane&15 (= h), row=q4*4+reg (= d within tile) -> f4 stores along d.
    const int w = tid >> 6;
    const int lane = tid & 63;
    const int m = lane & 15;
    const int q4 = lane >> 4;
    const int pass = w >> 1;           // waves 0,1 -> pass0; 2,3 -> pass1
    const int nbase = (w & 1) << 4;

    const unsigned short* RF = pass ? Rb : RT;
    s8v rf[4][2];
#pragma unroll
    for (int t = 0; t < 4; ++t) {
        rf[t][0] = *(const s8v*)&RF[(t * 16 + m) * BST + q4 * 8];
        rf[t][1] = *(const s8v*)&RF[(t * 16 + m) * BST + 32 + q4 * 8];
    }

    const int yy = pass ? (31 - y) : y;
    const int xx = pass ? (31 - x) : x;
    const size_t pos = (size_t)(yy * 32 + xx) * 1024;

    for (int i = 0; i < 16; ++i) {
        const int n = nbase + i;
        const size_t nb = (size_t)n << 20;   // n stride = H*W*h*d = 1048576 floats
        const float* src = in + nb + pos + m * 64 + q4 * 8;
        f4 u0 = *(const f4*)src;
        f4 u1 = *(const f4*)(src + 4);
        f4 u2 = *(const f4*)(src + 32);
        f4 u3 = *(const f4*)(src + 36);
        s8v b0, b1;
        b0[0] = (short)f2bf(u0.x); b0[1] = (short)f2bf(u0.y);
        b0[2] = (short)f2bf(u0.z); b0[3] = (short)f2bf(u0.w);
        b0[4] = (short)f2bf(u1.x); b0[5] = (short)f2bf(u1.y);
        b0[6] = (short)f2bf(u1.z); b0[7] = (short)f2bf(u1.w);
        b1[0] = (short)f2bf(u2.x); b1[1] = (short)f2bf(u2.y);
        b1[2] = (short)f2bf(u2.z); b1[3] = (short)f2bf(u2.w);
        b1[4] = (short)f2bf(u3.x); b1[5] = (short)f2bf(u3.y);
        b1[6] = (short)f2bf(u3.z); b1[7] = (short)f2bf(u3.w);

        f32x4 acc0 = {0.f,0.f,0.f,0.f}, acc1 = acc0, acc2 = acc0, acc3 = acc0;
        acc0 = __builtin_amdgcn_mfma_f32_16x16x32_bf16(rf[0][0], b0, acc0, 0, 0, 0);
        acc0 = __builtin_amdgcn_mfma_f32_16x16x32_bf16(rf[0][1], b1, acc0, 0, 0, 0);
        acc1 = __builtin_amdgcn_mfma_f32_16x16x32_bf16(rf[1][0], b0, acc1, 0, 0, 0);
        acc1 = __builtin_amdgcn_mfma_f32_16x16x32_bf16(rf[1][1], b1, acc1, 0, 0, 0);
        acc2 = __builtin_amdgcn_mfma_f32_16x16x32_bf16(rf[2][0], b0, acc2, 0, 0, 0);
        acc2 = __builtin_amdgcn_mfma_f32_16x16x32_bf16(rf[2][1], b1, acc2, 0, 0, 0);
        acc3 = __builtin_amdgcn_mfma_f32_16x16x32_bf16(rf[3][0], b0, acc3, 0, 0, 0);
        acc3 = __builtin_amdgcn_mfma_f32_16x16x32_bf16(rf[3][1], b1, acc3, 0, 0, 0);

        float* dst = out + nb + pos + m * 64 + q4 * 4;
        f4 o0 = {acc0[0], acc0[1], acc0[2], acc0[3]};
        f4 o1 = {acc1[0], acc1[1], acc1[2], acc1[3]};
        f4 o2 = {acc2[0], acc2[1], acc2[2], acc2[3]};
        f4 o3 = {acc3[0], acc3[1], acc3[2], acc3[3]};
        *(f4*)(dst +  0) = o0;
        *(f4*)(dst + 16) = o1;
        *(f4*)(dst + 32) = o2;
        *(f4*)(dst + 48) = o3;
    }
}

extern "C" void kernel_launch(void* const* d_in, const int* in_sizes, int n_in,
                              void* d_out, int out_size, void* d_ws, size_t ws_size,
                              hipStream_t stream) {
    (void)in_sizes; (void)n_in; (void)out_size; (void)d_ws; (void)ws_size;
    const float* in = (const float*)d_in[0];
    const float* emb = (const float*)d_in[1];
    float* out = (float*)d_out;
    hipLaunchKernelGGL(liere_fused, dim3(512), dim3(256), 0, stream, in, emb, out);
}